// Round 2
// baseline (727.164 us; speedup 1.0000x reference)
//
#include <hip/hip_runtime.h>
#include <stdint.h>

#define S_LEN 2048
#define DK 64
#define MT 64          // q rows per block
#define NT 64          // k cols per tile step
#define LD 72          // fallback LDS stride

typedef __attribute__((ext_vector_type(8))) short bf16x8;
typedef __attribute__((ext_vector_type(4))) float floatx4;
typedef __attribute__((ext_vector_type(16))) float f32x16;
typedef __attribute__((ext_vector_type(2))) unsigned int uint2v;

__device__ inline unsigned short f2bf(float f) {
    union { float f; unsigned u; } v; v.f = f;
    unsigned r = v.u + 0x7FFFu + ((v.u >> 16) & 1u);   // RNE
    return (unsigned short)(r >> 16);
}

// async global->LDS, 16B per lane. LDS dest = wave-uniform base + lane*16;
// we pass per-lane l = base + lane*16 so both semantics agree.
__device__ inline void async16(const void* g, void* l) {
    using gu32 = const __attribute__((address_space(1))) unsigned int;
    using lu32 = __attribute__((address_space(3))) unsigned int;
    gu32* gp = reinterpret_cast<gu32*>(reinterpret_cast<uintptr_t>(g));
    lu32* lp = reinterpret_cast<lu32*>(static_cast<unsigned int>(reinterpret_cast<uintptr_t>(l)));
    __builtin_amdgcn_global_load_lds(gp, lp, 16, 0, 0);
}

// st-style XOR swizzle within an 8KB 64x128B tile: flip byte bits[6:4] by row&7.
// Involution: applied to the GLOBAL source at staging (LDS dest must stay linear
// for global_load_lds) and again at the ds_read address -> identity on data,
// conflict-free column-slice reads.
__device__ inline unsigned swz(unsigned o) { return o ^ ((o >> 3) & 0x70u); }

__device__ inline void stage8k(const char* g, char* l, int wave, int lane) {
    const unsigned o0 = (unsigned)(wave * 2048 + lane * 16);
    async16(g + swz(o0), l + o0);
    async16(g + swz(o0 + 1024), l + o0 + 1024);
}

// Vt tile: rows d (stride 4096B in global), 128B window at col kt*128
__device__ inline void stageV(const char* Vh, int kt, char* l, int wave, int lane) {
    const unsigned o0 = (unsigned)(wave * 2048 + lane * 16);
    #pragma unroll
    for (int j = 0; j < 2; ++j) {
        const unsigned o = o0 + j * 1024;
        const unsigned s = swz(o);
        async16(Vh + (size_t)(o >> 7) * 4096 + kt * 128 + (s & 127), l + o);
    }
}

// ---------------- prologue: fp32 -> bf16 conversions ----------------
// Q gets the 1/sqrt(64)=0.125 scale folded in (exact in bf16: pow2).
__global__ __launch_bounds__(256) void convert_qk(
    const float* __restrict__ Q, const float* __restrict__ K,
    unsigned short* __restrict__ Qb, unsigned short* __restrict__ Kb)
{
    int i = blockIdx.x * 256 + threadIdx.x;        // 0 .. 2M-1 float4 chunks
    const int NQ = (2 * 16 * 2048 * 64) / 4;       // 1,048,576
    const float* src; unsigned short* dst; int j; float sc;
    if (i < NQ) { src = Q; dst = Qb; j = i; sc = 0.125f; }
    else        { src = K; dst = Kb; j = i - NQ; sc = 1.0f; }
    float4 f = ((const float4*)src)[j];
    ushort4 o;
    o.x = f2bf(f.x * sc); o.y = f2bf(f.y * sc);
    o.z = f2bf(f.z * sc); o.w = f2bf(f.w * sc);
    ((ushort4*)dst)[j] = o;
}

// V [head][k][d] fp32  ->  Vt [head][d][k] bf16, 64x64 tiles via LDS
__global__ __launch_bounds__(256) void transpose_v(
    const float* __restrict__ V, unsigned short* __restrict__ Vt)
{
    __shared__ unsigned short t[64][72];
    const int head = blockIdx.y, kt = blockIdx.x, tid = threadIdx.x;
    const float* src = V + ((size_t)head * S_LEN + kt * 64) * DK;
    {
        const int r = tid >> 2, c = (tid & 3) * 16;
        #pragma unroll
        for (int i = 0; i < 4; ++i) {
            float4 f = *(const float4*)(src + r * DK + c + i * 4);
            t[r][c + i * 4 + 0] = f2bf(f.x);
            t[r][c + i * 4 + 1] = f2bf(f.y);
            t[r][c + i * 4 + 2] = f2bf(f.z);
            t[r][c + i * 4 + 3] = f2bf(f.w);
        }
    }
    __syncthreads();
    {
        const int d = tid >> 2, kb = (tid & 3) * 16;
        unsigned short tmp[16];
        #pragma unroll
        for (int j = 0; j < 16; ++j) tmp[j] = t[kb + j][d];
        unsigned short* dst = Vt + (size_t)head * DK * S_LEN + (size_t)d * S_LEN + kt * 64 + kb;
        ((uint4*)dst)[0] = *(const uint4*)&tmp[0];
        ((uint4*)dst)[1] = *(const uint4*)&tmp[8];
    }
}

// ---------------- main kernel ----------------
// Swapped-operand 32x32x16 structure + T4 counted-vmcnt pipeline:
// per iteration: issue stage(t+1) -> s_waitcnt vmcnt(N) (N counts the in-flight
// prefetch + prior stores; guarantees stage(t) resident, in-order retire) ->
// raw s_barrier -> compute -> raw s_barrier (WAR fence, no drain).
// The per-iteration vmcnt(0) drain of __syncthreads (m233: ~70% of 2-phase
// loop time) is eliminated.
__global__ __launch_bounds__(256) void sdpa_main(
    const unsigned short* __restrict__ Qb, const unsigned short* __restrict__ Kb,
    const unsigned short* __restrict__ Vt, const int* __restrict__ mask,
    float* __restrict__ O, float* __restrict__ W)
{
    __shared__ alignas(16) char lds[32768];
    __shared__ float red[4][32];
    __shared__ unsigned mwords[64];

    const int tid  = threadIdx.x;
    const int wave = tid >> 6;
    const int lane = tid & 63;
    const int l31  = lane & 31;
    const int hi   = lane >> 5;
    const int qg   = wave >> 1;
    const int kb   = wave & 1;

    const int head = blockIdx.y;
    const int bidx = head >> 4;
    const int q0   = blockIdx.x * MT;

    const char* Qh = (const char*)(Qb + ((size_t)head * S_LEN + q0) * DK);
    const char* Kh = (const char*)(Kb + (size_t)head * S_LEN * DK);
    const char* Vh = (const char*)(Vt + (size_t)head * DK * S_LEN);
    const int*  mk = mask + bidx * S_LEN;
    float* Wh = W + (size_t)head * S_LEN * S_LEN;
    float* Oh = O + (size_t)head * S_LEN * DK;

    char* B0 = lds;             // Q, then V parity-0 (pass 2)
    char* B1 = lds + 8192;      // K parity-0
    char* B2 = lds + 16384;     // K parity-1
    char* B3 = lds + 24576;     // V parity-1 (pass 2)

    stage8k(Qh, B0, wave, lane);
    stage8k(Kh, B1, wave, lane);
    // build mask bit-words once (removes global mask loads from the hot loop)
    if (tid < 64) {
        const int* mb = mk + tid * 32;
        unsigned w = 0;
        #pragma unroll
        for (int i = 0; i < 32; ++i) w |= (mb[i] != 0 ? 1u : 0u) << i;
        mwords[tid] = w;
    }
    __syncthreads();   // full drain once: Q+K0 resident, mwords visible

    bf16x8 qf[4];
    {
        const unsigned rq = (unsigned)(qg * 32 + l31) * 128;
        #pragma unroll
        for (int m = 0; m < 4; ++m)
            qf[m] = *(const bf16x8*)(B0 + swz(rq + m * 32 + hi * 16));
    }

    const unsigned rk = (unsigned)(kb * 32 + l31) * 128;

    // ============ pass 1: masked-exp row sums (no max needed) ============
    float lsum = 0.f;
    for (int t = 0; t < 32; ++t) {
        char* cur = (t & 1) ? B2 : B1;
        if (t < 31) {
            stage8k(Kh + (size_t)(t + 1) * 8192, (t & 1) ? B1 : B2, wave, lane);
            asm volatile("s_waitcnt vmcnt(2)" ::: "memory");   // K(t) resident, K(t+1) in flight
        } else {
            asm volatile("s_waitcnt vmcnt(0)" ::: "memory");
        }
        __builtin_amdgcn_s_barrier();
        const unsigned mw = mwords[t * 2 + kb];
        f32x16 z;
        #pragma unroll
        for (int r = 0; r < 16; ++r) z[r] = 0.f;
        __builtin_amdgcn_s_setprio(1);
        #pragma unroll
        for (int m = 0; m < 4; ++m) {
            bf16x8 kf = *(const bf16x8*)(cur + swz(rk + m * 32 + hi * 16));
            z = __builtin_amdgcn_mfma_f32_32x32x16_bf16(kf, qf[m], z, 0, 0, 0);
        }
        __builtin_amdgcn_s_setprio(0);
        #pragma unroll
        for (int r = 0; r < 16; ++r) {
            const int kl = (r & 3) + 8 * (r >> 2) + 4 * hi;
            lsum += ((mw >> kl) & 1u) ? __expf(z[r]) : 0.f;
        }
        __builtin_amdgcn_s_barrier();   // WAR fence (no drain): reads of cur done
    }
    lsum += __shfl_xor(lsum, 32);
    if (hi == 0) red[wave][l31] = lsum;
    __syncthreads();
    const float rl = 1.0f / (red[qg * 2][l31] + red[qg * 2 + 1][l31]);

    // ============ pass 2: W + O ============
    f32x16 oacc0, oacc1;
    #pragma unroll
    for (int r = 0; r < 16; ++r) { oacc0[r] = 0.f; oacc1[r] = 0.f; }

    stage8k(Kh, B1, wave, lane);
    stageV(Vh, 0, B0, wave, lane);     // B0 (Q) now reused for V parity-0

    for (int t = 0; t < 32; ++t) {
        char* curK = (t & 1) ? B2 : B1;
        char* curV = (t & 1) ? B3 : B0;
        if (t < 31) {
            stage8k(Kh + (size_t)(t + 1) * 8192, (t & 1) ? B1 : B2, wave, lane);
            stageV(Vh, t + 1, (t & 1) ? B0 : B3, wave, lane);
        }
        // vmcnt accounting (in-order retire): newest-allowed =
        //   t==0 : stage(1)=4
        //   1..30: stage(t+1)=4 + stores(t-1)=4 -> 8
        //   t==31: stores(30)=4
        if (t == 0)      asm volatile("s_waitcnt vmcnt(4)" ::: "memory");
        else if (t < 31) asm volatile("s_waitcnt vmcnt(8)" ::: "memory");
        else             asm volatile("s_waitcnt vmcnt(4)" ::: "memory");
        __builtin_amdgcn_s_barrier();

        const unsigned mw = mwords[t * 2 + kb];
        f32x16 z;
        #pragma unroll
        for (int r = 0; r < 16; ++r) z[r] = 0.f;
        __builtin_amdgcn_s_setprio(1);
        #pragma unroll
        for (int m = 0; m < 4; ++m) {
            bf16x8 kf = *(const bf16x8*)(curK + swz(rk + m * 32 + hi * 16));
            z = __builtin_amdgcn_mfma_f32_32x32x16_bf16(kf, qf[m], z, 0, 0, 0);
        }
        __builtin_amdgcn_s_setprio(0);
        // normalize + mask in place
        #pragma unroll
        for (int r = 0; r < 16; ++r) {
            const int kl = (r & 3) + 8 * (r >> 2) + 4 * hi;
            const float e = __expf(z[r]) * rl;
            z[r] = ((mw >> kl) & 1u) ? e : 0.f;
        }
        // W: 4 x float4 per thread (rows q0+qg*32+l31, cols t*64+kb*32+8g+4hi)
        {
            float* wp = Wh + (size_t)(q0 + qg * 32 + l31) * S_LEN + t * 64 + kb * 32 + 4 * hi;
            #pragma unroll
            for (int g = 0; g < 4; ++g)
                *(float4*)(wp + 8 * g) = make_float4(z[4*g], z[4*g+1], z[4*g+2], z[4*g+3]);
        }
        // pack P to bf16 pairs: pk0[g] = (kl=8g+4hi, +1), pk1[g] = (+2, +3)
        unsigned pk0[4], pk1[4];
        #pragma unroll
        for (int g = 0; g < 4; ++g) {
            pk0[g] = (unsigned)f2bf(z[4*g+0]) | ((unsigned)f2bf(z[4*g+1]) << 16);
            pk1[g] = (unsigned)f2bf(z[4*g+2]) | ((unsigned)f2bf(z[4*g+3]) << 16);
        }
        // PV: permlane32_swap builds A-frag dwords d={p (lo|lo), p+2 (hi|hi)}
        __builtin_amdgcn_s_setprio(1);
        #pragma unroll
        for (int m2 = 0; m2 < 2; ++m2) {
            uint2v s0 = __builtin_amdgcn_permlane32_swap(pk0[2*m2], pk0[2*m2+1], false, false);
            uint2v s1 = __builtin_amdgcn_permlane32_swap(pk1[2*m2], pk1[2*m2+1], false, false);
            union { unsigned u[4]; bf16x8 v; } pa;
            pa.u[0] = s0[0]; pa.u[1] = s1[0]; pa.u[2] = s0[1]; pa.u[3] = s1[1];
            const unsigned cv = (unsigned)(kb * 64 + m2 * 32 + hi * 16);
            bf16x8 v0 = *(const bf16x8*)(curV + swz((unsigned)l31 * 128 + cv));
            bf16x8 v1 = *(const bf16x8*)(curV + swz((unsigned)(32 + l31) * 128 + cv));
            oacc0 = __builtin_amdgcn_mfma_f32_32x32x16_bf16(v0, pa.v, oacc0, 0, 0, 0);
            oacc1 = __builtin_amdgcn_mfma_f32_32x32x16_bf16(v1, pa.v, oacc1, 0, 0, 0);
        }
        __builtin_amdgcn_s_setprio(0);
        __builtin_amdgcn_s_barrier();   // WAR fence (no drain)
    }

    // ---- cross-wave (kb) O reduction via reused LDS, then store ----
    __syncthreads();                    // drain + ensure all LDS reads done before reuse
    float* redO = (float*)lds;
    if (kb == 1) {
        float* dst = redO + (size_t)(qg * 64 + lane) * 32;
        #pragma unroll
        for (int r = 0; r < 16; ++r) { dst[r] = oacc0[r]; dst[16 + r] = oacc1[r]; }
    }
    __syncthreads();
    if (kb == 0) {
        const float* sp = redO + (size_t)(qg * 64 + lane) * 32;
        #pragma unroll
        for (int r = 0; r < 16; ++r) { oacc0[r] += sp[r]; oacc1[r] += sp[16 + r]; }
        float* op = Oh + (size_t)(q0 + qg * 32 + l31) * DK + 4 * hi;
        #pragma unroll
        for (int g = 0; g < 4; ++g) {
            *(float4*)(op + 8 * g)      = make_float4(oacc0[4*g], oacc0[4*g+1], oacc0[4*g+2], oacc0[4*g+3]);
            *(float4*)(op + 32 + 8 * g) = make_float4(oacc1[4*g], oacc1[4*g+1], oacc1[4*g+2], oacc1[4*g+3]);
        }
    }
}

// ---------------- fallback (R1 kernel, used only if ws too small) ----------------
__global__ __launch_bounds__(256) void sdpa_fb(
    const float* __restrict__ Q, const float* __restrict__ K,
    const float* __restrict__ V, const int* __restrict__ mask,
    float* __restrict__ O, float* __restrict__ W)
{
    __shared__ alignas(16) unsigned short qs[MT * LD];
    __shared__ alignas(16) unsigned short ks[NT * LD];
    __shared__ alignas(16) unsigned short vs[DK * LD];
    __shared__ alignas(16) unsigned short ps[MT * LD];
    __shared__ float addm[NT];

    const int tid = threadIdx.x, wave = tid >> 6, lane = tid & 63;
    const int quad = lane >> 4, l16 = lane & 15;
    const int head = blockIdx.y, bidx = head >> 4, q0 = blockIdx.x * MT;

    const float* Qh = Q + (size_t)head * S_LEN * DK;
    const float* Kh = K + (size_t)head * S_LEN * DK;
    const float* Vh = V + (size_t)head * S_LEN * DK;
    const int* mk = mask + bidx * S_LEN;
    float* Wh = W + (size_t)head * S_LEN * S_LEN;
    float* Oh = O + (size_t)head * S_LEN * DK;

    #pragma unroll
    for (int i = 0; i < 4; ++i) {
        const int g = i * 256 + tid, row = g >> 4, col = (g & 15) * 4;
        float4 f = *(const float4*)(Qh + (size_t)(q0 + row) * DK + col);
        unsigned* d = (unsigned*)&qs[row * LD + col];
        d[0] = f2bf(f.x) | ((unsigned)f2bf(f.y) << 16);
        d[1] = f2bf(f.z) | ((unsigned)f2bf(f.w) << 16);
    }
    __syncthreads();
    const bf16x8 qa0 = *(const bf16x8*)&qs[(wave * 16 + l16) * LD + quad * 8];
    const bf16x8 qa1 = *(const bf16x8*)&qs[(wave * 16 + l16) * LD + 32 + quad * 8];

    float m[4], l[4];
    #pragma unroll
    for (int r = 0; r < 4; ++r) { m[r] = -1e30f; l[r] = 0.0f; }

    for (int kt = 0; kt < S_LEN / NT; ++kt) {
        #pragma unroll
        for (int i = 0; i < 4; ++i) {
            const int g = i * 256 + tid, row = g >> 4, col = (g & 15) * 4;
            float4 f = *(const float4*)(Kh + (size_t)(kt * NT + row) * DK + col);
            unsigned* d = (unsigned*)&ks[row * LD + col];
            d[0] = f2bf(f.x) | ((unsigned)f2bf(f.y) << 16);
            d[1] = f2bf(f.z) | ((unsigned)f2bf(f.w) << 16);
        }
        if (tid < NT) addm[tid] = mk[kt * NT + tid] ? 0.0f : -1e30f;
        __syncthreads();
        floatx4 acc[4];
        #pragma unroll
        for (int c = 0; c < 4; ++c) {
            bf16x8 b0 = *(const bf16x8*)&ks[(c * 16 + l16) * LD + quad * 8];
            bf16x8 b1 = *(const bf16x8*)&ks[(c * 16 + l16) * LD + 32 + quad * 8];
            floatx4 z = {0.f, 0.f, 0.f, 0.f};
            z = __builtin_amdgcn_mfma_f32_16x16x32_bf16(qa0, b0, z, 0, 0, 0);
            z = __builtin_amdgcn_mfma_f32_16x16x32_bf16(qa1, b1, z, 0, 0, 0);
            acc[c] = z;
        }
        float sv[4][4];
        #pragma unroll
        for (int c = 0; c < 4; ++c) {
            float am = addm[c * 16 + l16];
            #pragma unroll
            for (int r = 0; r < 4; ++r) sv[c][r] = acc[c][r] * 0.125f + am;
        }
        #pragma unroll
        for (int r = 0; r < 4; ++r) {
            float tmax = fmaxf(fmaxf(sv[0][r], sv[1][r]), fmaxf(sv[2][r], sv[3][r]));
            #pragma unroll
            for (int off = 1; off < 16; off <<= 1) tmax = fmaxf(tmax, __shfl_xor(tmax, off, 64));
            float mn = fmaxf(m[r], tmax);
            float ts = __expf(sv[0][r] - mn) + __expf(sv[1][r] - mn)
                     + __expf(sv[2][r] - mn) + __expf(sv[3][r] - mn);
            #pragma unroll
            for (int off = 1; off < 16; off <<= 1) ts += __shfl_xor(ts, off, 64);
            l[r] = l[r] * __expf(m[r] - mn) + ts;
            m[r] = mn;
        }
        __syncthreads();
    }
    float rl[4];
    #pragma unroll
    for (int r = 0; r < 4; ++r) rl[r] = 1.0f / l[r];

    floatx4 oacc[4];
    #pragma unroll
    for (int c = 0; c < 4; ++c) oacc[c] = (floatx4){0.f, 0.f, 0.f, 0.f};

    for (int kt = 0; kt < S_LEN / NT; ++kt) {
        #pragma unroll
        for (int i = 0; i < 4; ++i) {
            const int g = i * 256 + tid, row = g >> 4, col = (g & 15) * 4;
            float4 f = *(const float4*)(Kh + (size_t)(kt * NT + row) * DK + col);
            unsigned* d = (unsigned*)&ks[row * LD + col];
            d[0] = f2bf(f.x) | ((unsigned)f2bf(f.y) << 16);
            d[1] = f2bf(f.z) | ((unsigned)f2bf(f.w) << 16);
        }
        {
            const int row = tid >> 2, colg = (tid & 3) << 4;
            const float4* vsrc = (const float4*)(Vh + (size_t)(kt * NT + row) * DK + colg);
            #pragma unroll
            for (int i = 0; i < 4; ++i) {
                float4 f = vsrc[i];
                const int dbase = colg + i * 4;
                vs[(dbase + 0) * LD + row] = f2bf(f.x);
                vs[(dbase + 1) * LD + row] = f2bf(f.y);
                vs[(dbase + 2) * LD + row] = f2bf(f.z);
                vs[(dbase + 3) * LD + row] = f2bf(f.w);
            }
        }
        if (tid < NT) addm[tid] = mk[kt * NT + tid] ? 0.0f : -1e30f;
        __syncthreads();
        floatx4 acc[4];
        #pragma unroll
        for (int c = 0; c < 4; ++c) {
            bf16x8 b0 = *(const bf16x8*)&ks[(c * 16 + l16) * LD + quad * 8];
            bf16x8 b1 = *(const bf16x8*)&ks[(c * 16 + l16) * LD + 32 + quad * 8];
            floatx4 z = {0.f, 0.f, 0.f, 0.f};
            z = __builtin_amdgcn_mfma_f32_16x16x32_bf16(qa0, b0, z, 0, 0, 0);
            z = __builtin_amdgcn_mfma_f32_16x16x32_bf16(qa1, b1, z, 0, 0, 0);
            acc[c] = z;
        }
        #pragma unroll
        for (int c = 0; c < 4; ++c) {
            float am = addm[c * 16 + l16];
            #pragma unroll
            for (int r = 0; r < 4; ++r) {
                const int lrow = wave * 16 + quad * 4 + r;
                float w = __expf(acc[c][r] * 0.125f + am - m[r]) * rl[r];
                Wh[(size_t)(q0 + lrow) * S_LEN + kt * NT + c * 16 + l16] = w;
                ps[lrow * LD + c * 16 + l16] = f2bf(w);
            }
        }
        __syncthreads();
        bf16x8 pa0 = *(const bf16x8*)&ps[(wave * 16 + l16) * LD + quad * 8];
        bf16x8 pa1 = *(const bf16x8*)&ps[(wave * 16 + l16) * LD + 32 + quad * 8];
        #pragma unroll
        for (int c = 0; c < 4; ++c) {
            bf16x8 v0 = *(const bf16x8*)&vs[(c * 16 + l16) * LD + quad * 8];
            bf16x8 v1 = *(const bf16x8*)&vs[(c * 16 + l16) * LD + 32 + quad * 8];
            oacc[c] = __builtin_amdgcn_mfma_f32_16x16x32_bf16(pa0, v0, oacc[c], 0, 0, 0);
            oacc[c] = __builtin_amdgcn_mfma_f32_16x16x32_bf16(pa1, v1, oacc[c], 0, 0, 0);
        }
        __syncthreads();
    }
    #pragma unroll
    for (int c = 0; c < 4; ++c) {
        #pragma unroll
        for (int r = 0; r < 4; ++r) {
            const int lrow = wave * 16 + quad * 4 + r;
            Oh[(size_t)(q0 + lrow) * DK + c * 16 + l16] = oacc[c][r];
        }
    }
}

extern "C" void kernel_launch(void* const* d_in, const int* in_sizes, int n_in,
                              void* d_out, int out_size, void* d_ws, size_t ws_size,
                              hipStream_t stream) {
    const float* Q  = (const float*)d_in[0];
    const float* K  = (const float*)d_in[1];
    const float* V  = (const float*)d_in[2];
    const int* mask = (const int*)d_in[3];

    float* O = (float*)d_out;                                  // [2,16,2048,64]
    float* W = (float*)d_out + (size_t)2 * 16 * 2048 * 64;     // [2,16,2048,2048]

    const size_t elems = (size_t)2 * 16 * 2048 * 64;           // 4,194,304
    const size_t need  = 3 * elems * sizeof(unsigned short);   // 24 MiB

    if (ws_size >= need) {
        unsigned short* Qb = (unsigned short*)d_ws;
        unsigned short* Kb = Qb + elems;
        unsigned short* Vt = Kb + elems;
        convert_qk<<<dim3((2 * elems / 4) / 256), 256, 0, stream>>>(Q, K, Qb, Kb);
        transpose_v<<<dim3(32, 32), 256, 0, stream>>>(V, Vt);
        sdpa_main<<<dim3(S_LEN / MT, 32), 256, 0, stream>>>(Qb, Kb, Vt, mask, O, W);
    } else {
        sdpa_fb<<<dim3(S_LEN / MT, 32), 256, 0, stream>>>(Q, K, V, mask, O, W);
    }
}

// Round 3
// 680.001 us; speedup vs baseline: 1.0694x; 1.0694x over previous
//
#include <hip/hip_runtime.h>
#include <stdint.h>

#define S_LEN 2048
#define DK 64
#define MT 64          // q rows per block
#define NT 64          // k cols per tile step
#define LDP 72         // ps stride in ushort (144B, 16B-aligned)

typedef __attribute__((ext_vector_type(8))) short bf16x8;
typedef __attribute__((ext_vector_type(4))) float floatx4;

__device__ inline unsigned short f2bf(float f) {
    union { float f; unsigned u; } v; v.f = f;
    unsigned r = v.u + 0x7FFFu + ((v.u >> 16) & 1u);   // RNE
    return (unsigned short)(r >> 16);
}

// async global->LDS, 16B per lane. LDS dest = wave-uniform base + lane*16;
// we pass per-lane l = base + lane*16 so both semantics agree.
__device__ inline void async16(const void* g, void* l) {
    using gu32 = const __attribute__((address_space(1))) unsigned int;
    using lu32 = __attribute__((address_space(3))) unsigned int;
    gu32* gp = reinterpret_cast<gu32*>(reinterpret_cast<uintptr_t>(g));
    lu32* lp = reinterpret_cast<lu32*>(static_cast<unsigned int>(reinterpret_cast<uintptr_t>(l)));
    __builtin_amdgcn_global_load_lds(gp, lp, 16, 0, 0);
}

// XOR swizzle within an 8KB 64x128B tile: flip byte bits[6:4] by row&7.
// Involution. Applied to the GLOBAL source at staging (LDS dest must stay
// linear for global_load_lds, G21) and again on the ds_read address ->
// identity on data; b128 column-slice reads go from 16-way conflict to ~2-way.
__device__ inline unsigned swz(unsigned o) { return o ^ ((o >> 3) & 0x70u); }

__device__ inline void stage8k(const char* g, char* l, int wave, int lane) {
    const unsigned o0 = (unsigned)(wave * 2048 + lane * 16);
    async16(g + swz(o0), l + o0);
    async16(g + swz(o0 + 1024), l + o0 + 1024);
}

// Vt tile: rows d (stride 4096B in global), 128B window at col kt*128,
// source column taken at the swizzled offset so a swizzled read is identity.
__device__ inline void stageV(const char* Vh, int kt, char* l, int wave, int lane) {
    const unsigned o0 = (unsigned)(wave * 2048 + lane * 16);
    #pragma unroll
    for (int j = 0; j < 2; ++j) {
        const unsigned o = o0 + j * 1024;
        const unsigned s = swz(o);
        async16(Vh + (size_t)(o >> 7) * 4096 + kt * 128 + (s & 127), l + o);
    }
}

// ---------------- prologue: fp32 -> bf16 conversions ----------------
// Q gets the 1/sqrt(64)=0.125 scale folded in (exact in bf16: pow2).
__global__ __launch_bounds__(256) void convert_qk(
    const float* __restrict__ Q, const float* __restrict__ K,
    unsigned short* __restrict__ Qb, unsigned short* __restrict__ Kb)
{
    int i = blockIdx.x * 256 + threadIdx.x;        // 0 .. 2M-1 float4 chunks
    const int NQ = (2 * 16 * 2048 * 64) / 4;       // 1,048,576
    const float* src; unsigned short* dst; int j; float sc;
    if (i < NQ) { src = Q; dst = Qb; j = i; sc = 0.125f; }
    else        { src = K; dst = Kb; j = i - NQ; sc = 1.0f; }
    float4 f = ((const float4*)src)[j];
    ushort4 o;
    o.x = f2bf(f.x * sc); o.y = f2bf(f.y * sc);
    o.z = f2bf(f.z * sc); o.w = f2bf(f.w * sc);
    ((ushort4*)dst)[j] = o;
}

// V [head][k][d] fp32  ->  Vt [head][d][k] bf16, 64x64 tiles via LDS
__global__ __launch_bounds__(256) void transpose_v(
    const float* __restrict__ V, unsigned short* __restrict__ Vt)
{
    __shared__ unsigned short t[64][72];
    const int head = blockIdx.y, kt = blockIdx.x, tid = threadIdx.x;
    const float* src = V + ((size_t)head * S_LEN + kt * 64) * DK;
    {
        const int r = tid >> 2, c = (tid & 3) * 16;
        #pragma unroll
        for (int i = 0; i < 4; ++i) {
            float4 f = *(const float4*)(src + r * DK + c + i * 4);
            t[r][c + i * 4 + 0] = f2bf(f.x);
            t[r][c + i * 4 + 1] = f2bf(f.y);
            t[r][c + i * 4 + 2] = f2bf(f.z);
            t[r][c + i * 4 + 3] = f2bf(f.w);
        }
    }
    __syncthreads();
    {
        const int d = tid >> 2, kb = (tid & 3) * 16;
        unsigned short tmp[16];
        #pragma unroll
        for (int j = 0; j < 16; ++j) tmp[j] = t[kb + j][d];
        unsigned short* dst = Vt + (size_t)head * DK * S_LEN + (size_t)d * S_LEN + kt * 64 + kb;
        ((uint4*)dst)[0] = *(const uint4*)&tmp[0];
        ((uint4*)dst)[1] = *(const uint4*)&tmp[8];
    }
}

// ---------------- main kernel ----------------
// EXACT R0 structure (16x16x32 MFMA, __syncthreads barriers, gathered mask,
// ps round-trip, scalar W stores). ONLY change vs R0: qs/ks/vs staged with
// pre-swizzled global source and read at swizzled LDS addresses.
__global__ __launch_bounds__(256) void sdpa_main(
    const unsigned short* __restrict__ Qb, const unsigned short* __restrict__ Kb,
    const unsigned short* __restrict__ Vt, const int* __restrict__ mask,
    float* __restrict__ O, float* __restrict__ W)
{
    __shared__ alignas(16) unsigned short qs[MT * DK];   // unpadded (global_load_lds)
    __shared__ alignas(16) unsigned short ks[NT * DK];
    __shared__ alignas(16) unsigned short vs[DK * NT];   // [d][k]
    __shared__ alignas(16) unsigned short ps[MT * LDP];

    const int tid  = threadIdx.x;
    const int wave = tid >> 6;
    const int lane = tid & 63;
    const int quad = lane >> 4;
    const int l16  = lane & 15;

    const int head = blockIdx.y;
    const int bidx = head >> 4;
    const int q0   = blockIdx.x * MT;

    const unsigned short* Qh = Qb + ((size_t)head * S_LEN + q0) * DK;
    const unsigned short* Kh = Kb + (size_t)head * S_LEN * DK;
    const unsigned short* Vh = Vt + (size_t)head * DK * S_LEN;
    const int*   mk = mask + bidx * S_LEN;
    float* Wh = W + (size_t)head * S_LEN * S_LEN;
    float* Oh = O + (size_t)head * S_LEN * DK;

    // stage Q tile (8 KB), swizzled source
    stage8k((const char*)Qh, (char*)qs, wave, lane);
    __syncthreads();
    const unsigned rq = (unsigned)(wave * 16 + l16) * 128 + (unsigned)quad * 16;
    const bf16x8 qa0 = *(const bf16x8*)((const char*)qs + swz(rq));
    const bf16x8 qa1 = *(const bf16x8*)((const char*)qs + swz(rq + 64));

    // ============ pass 1: denominators only (no max needed) ============
    float lsum[4] = {0.f, 0.f, 0.f, 0.f};
    for (int kt = 0; kt < S_LEN / NT; ++kt) {
        stage8k((const char*)Kh + kt * 8192, (char*)ks, wave, lane);
        float mf[4];
        #pragma unroll
        for (int c = 0; c < 4; ++c)
            mf[c] = mk[kt * NT + c * 16 + l16] ? 1.0f : 0.0f;
        __syncthreads();
        #pragma unroll
        for (int c = 0; c < 4; ++c) {
            const unsigned rk = (unsigned)(c * 16 + l16) * 128 + (unsigned)quad * 16;
            bf16x8 b0 = *(const bf16x8*)((const char*)ks + swz(rk));
            bf16x8 b1 = *(const bf16x8*)((const char*)ks + swz(rk + 64));
            floatx4 z = {0.f, 0.f, 0.f, 0.f};
            z = __builtin_amdgcn_mfma_f32_16x16x32_bf16(qa0, b0, z, 0, 0, 0);
            z = __builtin_amdgcn_mfma_f32_16x16x32_bf16(qa1, b1, z, 0, 0, 0);
            #pragma unroll
            for (int r = 0; r < 4; ++r)
                lsum[r] += __expf(z[r]) * mf[c];
        }
        __syncthreads();   // WAR before next staging
    }
    float rl[4];
    #pragma unroll
    for (int r = 0; r < 4; ++r) {
        float s = lsum[r];
        #pragma unroll
        for (int off = 1; off < 16; off <<= 1)
            s += __shfl_xor(s, off, 64);
        rl[r] = 1.0f / s;
    }

    // ============ pass 2: W + O ============
    floatx4 oacc[4];
    #pragma unroll
    for (int c = 0; c < 4; ++c) oacc[c] = (floatx4){0.f, 0.f, 0.f, 0.f};

    for (int kt = 0; kt < S_LEN / NT; ++kt) {
        stage8k((const char*)Kh + kt * 8192, (char*)ks, wave, lane);
        stageV((const char*)Vh, kt, (char*)vs, wave, lane);
        float mf[4];
        #pragma unroll
        for (int c = 0; c < 4; ++c)
            mf[c] = mk[kt * NT + c * 16 + l16] ? 1.0f : 0.0f;
        __syncthreads();

        floatx4 acc[4];
        #pragma unroll
        for (int c = 0; c < 4; ++c) {
            const unsigned rk = (unsigned)(c * 16 + l16) * 128 + (unsigned)quad * 16;
            bf16x8 b0 = *(const bf16x8*)((const char*)ks + swz(rk));
            bf16x8 b1 = *(const bf16x8*)((const char*)ks + swz(rk + 64));
            floatx4 z = {0.f, 0.f, 0.f, 0.f};
            z = __builtin_amdgcn_mfma_f32_16x16x32_bf16(qa0, b0, z, 0, 0, 0);
            z = __builtin_amdgcn_mfma_f32_16x16x32_bf16(qa1, b1, z, 0, 0, 0);
            acc[c] = z;
        }

        #pragma unroll
        for (int c = 0; c < 4; ++c) {
            #pragma unroll
            for (int r = 0; r < 4; ++r) {
                const int lrow = wave * 16 + quad * 4 + r;
                float w = __expf(acc[c][r]) * rl[r] * mf[c];
                Wh[(size_t)(q0 + lrow) * S_LEN + kt * NT + c * 16 + l16] = w;
                ps[lrow * LDP + c * 16 + l16] = f2bf(w);
            }
        }
        // same-wave LDS RAW (rows wave*16..+15): in-order LDS + compiler waitcnt
        bf16x8 pa0 = *(const bf16x8*)&ps[(wave * 16 + l16) * LDP + quad * 8];
        bf16x8 pa1 = *(const bf16x8*)&ps[(wave * 16 + l16) * LDP + 32 + quad * 8];
        #pragma unroll
        for (int c = 0; c < 4; ++c) {
            const unsigned rv = (unsigned)(c * 16 + l16) * 128 + (unsigned)quad * 16;
            bf16x8 v0 = *(const bf16x8*)((const char*)vs + swz(rv));
            bf16x8 v1 = *(const bf16x8*)((const char*)vs + swz(rv + 64));
            oacc[c] = __builtin_amdgcn_mfma_f32_16x16x32_bf16(pa0, v0, oacc[c], 0, 0, 0);
            oacc[c] = __builtin_amdgcn_mfma_f32_16x16x32_bf16(pa1, v1, oacc[c], 0, 0, 0);
        }
        __syncthreads();   // WAR: ks/vs re-staged, ps rewritten next iter
    }

    #pragma unroll
    for (int c = 0; c < 4; ++c) {
        #pragma unroll
        for (int r = 0; r < 4; ++r) {
            const int lrow = wave * 16 + quad * 4 + r;
            Oh[(size_t)(q0 + lrow) * DK + c * 16 + l16] = oacc[c][r];
        }
    }
}

// ---------------- fallback (used only if ws too small) ----------------
#define LD 72
__global__ __launch_bounds__(256) void sdpa_fb(
    const float* __restrict__ Q, const float* __restrict__ K,
    const float* __restrict__ V, const int* __restrict__ mask,
    float* __restrict__ O, float* __restrict__ W)
{
    __shared__ alignas(16) unsigned short qs[MT * LD];
    __shared__ alignas(16) unsigned short ks[NT * LD];
    __shared__ alignas(16) unsigned short vs[DK * LD];
    __shared__ alignas(16) unsigned short ps[MT * LD];
    __shared__ float addm[NT];

    const int tid = threadIdx.x, wave = tid >> 6, lane = tid & 63;
    const int quad = lane >> 4, l16 = lane & 15;
    const int head = blockIdx.y, bidx = head >> 4, q0 = blockIdx.x * MT;

    const float* Qh = Q + (size_t)head * S_LEN * DK;
    const float* Kh = K + (size_t)head * S_LEN * DK;
    const float* Vh = V + (size_t)head * S_LEN * DK;
    const int* mk = mask + bidx * S_LEN;
    float* Wh = W + (size_t)head * S_LEN * S_LEN;
    float* Oh = O + (size_t)head * S_LEN * DK;

    #pragma unroll
    for (int i = 0; i < 4; ++i) {
        const int g = i * 256 + tid, row = g >> 4, col = (g & 15) * 4;
        float4 f = *(const float4*)(Qh + (size_t)(q0 + row) * DK + col);
        unsigned* d = (unsigned*)&qs[row * LD + col];
        d[0] = f2bf(f.x) | ((unsigned)f2bf(f.y) << 16);
        d[1] = f2bf(f.z) | ((unsigned)f2bf(f.w) << 16);
    }
    __syncthreads();
    const bf16x8 qa0 = *(const bf16x8*)&qs[(wave * 16 + l16) * LD + quad * 8];
    const bf16x8 qa1 = *(const bf16x8*)&qs[(wave * 16 + l16) * LD + 32 + quad * 8];

    float m[4], l[4];
    #pragma unroll
    for (int r = 0; r < 4; ++r) { m[r] = -1e30f; l[r] = 0.0f; }

    for (int kt = 0; kt < S_LEN / NT; ++kt) {
        #pragma unroll
        for (int i = 0; i < 4; ++i) {
            const int g = i * 256 + tid, row = g >> 4, col = (g & 15) * 4;
            float4 f = *(const float4*)(Kh + (size_t)(kt * NT + row) * DK + col);
            unsigned* d = (unsigned*)&ks[row * LD + col];
            d[0] = f2bf(f.x) | ((unsigned)f2bf(f.y) << 16);
            d[1] = f2bf(f.z) | ((unsigned)f2bf(f.w) << 16);
        }
        if (tid < NT) addm[tid] = mk[kt * NT + tid] ? 0.0f : -1e30f;
        __syncthreads();
        floatx4 acc[4];
        #pragma unroll
        for (int c = 0; c < 4; ++c) {
            bf16x8 b0 = *(const bf16x8*)&ks[(c * 16 + l16) * LD + quad * 8];
            bf16x8 b1 = *(const bf16x8*)&ks[(c * 16 + l16) * LD + 32 + quad * 8];
            floatx4 z = {0.f, 0.f, 0.f, 0.f};
            z = __builtin_amdgcn_mfma_f32_16x16x32_bf16(qa0, b0, z, 0, 0, 0);
            z = __builtin_amdgcn_mfma_f32_16x16x32_bf16(qa1, b1, z, 0, 0, 0);
            acc[c] = z;
        }
        float sv[4][4];
        #pragma unroll
        for (int c = 0; c < 4; ++c) {
            float am = addm[c * 16 + l16];
            #pragma unroll
            for (int r = 0; r < 4; ++r) sv[c][r] = acc[c][r] * 0.125f + am;
        }
        #pragma unroll
        for (int r = 0; r < 4; ++r) {
            float tmax = fmaxf(fmaxf(sv[0][r], sv[1][r]), fmaxf(sv[2][r], sv[3][r]));
            #pragma unroll
            for (int off = 1; off < 16; off <<= 1) tmax = fmaxf(tmax, __shfl_xor(tmax, off, 64));
            float mn = fmaxf(m[r], tmax);
            float ts = __expf(sv[0][r] - mn) + __expf(sv[1][r] - mn)
                     + __expf(sv[2][r] - mn) + __expf(sv[3][r] - mn);
            #pragma unroll
            for (int off = 1; off < 16; off <<= 1) ts += __shfl_xor(ts, off, 64);
            l[r] = l[r] * __expf(m[r] - mn) + ts;
            m[r] = mn;
        }
        __syncthreads();
    }
    float rl[4];
    #pragma unroll
    for (int r = 0; r < 4; ++r) rl[r] = 1.0f / l[r];

    floatx4 oacc[4];
    #pragma unroll
    for (int c = 0; c < 4; ++c) oacc[c] = (floatx4){0.f, 0.f, 0.f, 0.f};

    for (int kt = 0; kt < S_LEN / NT; ++kt) {
        #pragma unroll
        for (int i = 0; i < 4; ++i) {
            const int g = i * 256 + tid, row = g >> 4, col = (g & 15) * 4;
            float4 f = *(const float4*)(Kh + (size_t)(kt * NT + row) * DK + col);
            unsigned* d = (unsigned*)&ks[row * LD + col];
            d[0] = f2bf(f.x) | ((unsigned)f2bf(f.y) << 16);
            d[1] = f2bf(f.z) | ((unsigned)f2bf(f.w) << 16);
        }
        {
            const int row = tid >> 2, colg = (tid & 3) << 4;
            const float4* vsrc = (const float4*)(Vh + (size_t)(kt * NT + row) * DK + colg);
            #pragma unroll
            for (int i = 0; i < 4; ++i) {
                float4 f = vsrc[i];
                const int dbase = colg + i * 4;
                vs[(dbase + 0) * LD + row] = f2bf(f.x);
                vs[(dbase + 1) * LD + row] = f2bf(f.y);
                vs[(dbase + 2) * LD + row] = f2bf(f.z);
                vs[(dbase + 3) * LD + row] = f2bf(f.w);
            }
        }
        if (tid < NT) addm[tid] = mk[kt * NT + tid] ? 0.0f : -1e30f;
        __syncthreads();
        floatx4 acc[4];
        #pragma unroll
        for (int c = 0; c < 4; ++c) {
            bf16x8 b0 = *(const bf16x8*)&ks[(c * 16 + l16) * LD + quad * 8];
            bf16x8 b1 = *(const bf16x8*)&ks[(c * 16 + l16) * LD + 32 + quad * 8];
            floatx4 z = {0.f, 0.f, 0.f, 0.f};
            z = __builtin_amdgcn_mfma_f32_16x16x32_bf16(qa0, b0, z, 0, 0, 0);
            z = __builtin_amdgcn_mfma_f32_16x16x32_bf16(qa1, b1, z, 0, 0, 0);
            acc[c] = z;
        }
        #pragma unroll
        for (int c = 0; c < 4; ++c) {
            float am = addm[c * 16 + l16];
            #pragma unroll
            for (int r = 0; r < 4; ++r) {
                const int lrow = wave * 16 + quad * 4 + r;
                float w = __expf(acc[c][r] * 0.125f + am - m[r]) * rl[r];
                Wh[(size_t)(q0 + lrow) * S_LEN + kt * NT + c * 16 + l16] = w;
                ps[lrow * LD + c * 16 + l16] = f2bf(w);
            }
        }
        __syncthreads();
        bf16x8 pa0 = *(const bf16x8*)&ps[(wave * 16 + l16) * LD + quad * 8];
        bf16x8 pa1 = *(const bf16x8*)&ps[(wave * 16 + l16) * LD + 32 + quad * 8];
        #pragma unroll
        for (int c = 0; c < 4; ++c) {
            bf16x8 v0 = *(const bf16x8*)&vs[(c * 16 + l16) * LD + quad * 8];
            bf16x8 v1 = *(const bf16x8*)&vs[(c * 16 + l16) * LD + 32 + quad * 8];
            oacc[c] = __builtin_amdgcn_mfma_f32_16x16x32_bf16(pa0, v0, oacc[c], 0, 0, 0);
            oacc[c] = __builtin_amdgcn_mfma_f32_16x16x32_bf16(pa1, v1, oacc[c], 0, 0, 0);
        }
        __syncthreads();
    }
    #pragma unroll
    for (int c = 0; c < 4; ++c) {
        #pragma unroll
        for (int r = 0; r < 4; ++r) {
            const int lrow = wave * 16 + quad * 4 + r;
            Oh[(size_t)(q0 + lrow) * DK + c * 16 + l16] = oacc[c][r];
        }
    }
}

extern "C" void kernel_launch(void* const* d_in, const int* in_sizes, int n_in,
                              void* d_out, int out_size, void* d_ws, size_t ws_size,
                              hipStream_t stream) {
    const float* Q  = (const float*)d_in[0];
    const float* K  = (const float*)d_in[1];
    const float* V  = (const float*)d_in[2];
    const int* mask = (const int*)d_in[3];

    float* O = (float*)d_out;                                  // [2,16,2048,64]
    float* W = (float*)d_out + (size_t)2 * 16 * 2048 * 64;     // [2,16,2048,2048]

    const size_t elems = (size_t)2 * 16 * 2048 * 64;           // 4,194,304
    const size_t need  = 3 * elems * sizeof(unsigned short);   // 24 MiB

    if (ws_size >= need) {
        unsigned short* Qb = (unsigned short*)d_ws;
        unsigned short* Kb = Qb + elems;
        unsigned short* Vt = Kb + elems;
        convert_qk<<<dim3((2 * elems / 4) / 256), 256, 0, stream>>>(Q, K, Qb, Kb);
        transpose_v<<<dim3(32, 32), 256, 0, stream>>>(V, Vt);
        sdpa_main<<<dim3(S_LEN / MT, 32), 256, 0, stream>>>(Qb, Kb, Vt, mask, O, W);
    } else {
        sdpa_fb<<<dim3(S_LEN / MT, 32), 256, 0, stream>>>(Q, K, V, mask, O, W);
    }
}